// Round 1
// baseline (322.117 us; speedup 1.0000x reference)
//
#include <hip/hip_runtime.h>
#include <math.h>

// HyperConnection: N=100000 independent problems, S=4, D=256.
// One 256-thread block per n; wave s (of 4) owns stream-row s.
static constexpr int SD = 4;     // S
static constexpr int DD = 256;   // D
static constexpr float INV_TAU = 10.0f;
static constexpr int NIT = 10;

__global__ __launch_bounds__(256) void hyperconn_kernel(
    const float* __restrict__ x_streams,       // (N,S,D)
    const float* __restrict__ message_output,  // (N,D)
    const float* __restrict__ theta_pre,       // (1,D)
    const float* __restrict__ b_pre,           // (1,S)
    const float* __restrict__ theta_post,      // (1,D)
    const float* __restrict__ b_post,          // (1,S)
    const float* __restrict__ Theta_res,       // (S,D)
    const float* __restrict__ B_res,           // (S,S)
    const float* __restrict__ alpha_pre_p,
    const float* __restrict__ alpha_post_p,
    const float* __restrict__ alpha_res_p,
    float* __restrict__ out_x,                 // (N,S,D)
    float* __restrict__ out_hpre)              // (N,S)
{
    const int n = blockIdx.x;
    const int t = threadIdx.x;
    const int s = t >> 6;   // wave id == stream row
    const int j = t & 63;   // lane == float4 column

    __shared__ float sx[SD][DD];        // raw x tile
    __shared__ float sdots[SD][6];      // per-row normalized dots
    __shared__ float sH[SD * SD + SD];  // H_res (16) then H_post (4)

    const size_t xbase = (size_t)n * (SD * DD);

    // ---- load my row's float4, stash raw x into LDS ----
    float4 xv = reinterpret_cast<const float4*>(x_streams + xbase + s * DD)[j];
    reinterpret_cast<float4*>(&sx[s][0])[j] = xv;

    // ---- small shared vectors (L1/L2-resident across all blocks) ----
    float4 tp = reinterpret_cast<const float4*>(theta_pre)[j];
    float4 tq = reinterpret_cast<const float4*>(theta_post)[j];
    float4 r0 = reinterpret_cast<const float4*>(Theta_res + 0 * DD)[j];
    float4 r1 = reinterpret_cast<const float4*>(Theta_res + 1 * DD)[j];
    float4 r2 = reinterpret_cast<const float4*>(Theta_res + 2 * DD)[j];
    float4 r3 = reinterpret_cast<const float4*>(Theta_res + 3 * DD)[j];

    // ---- 7 partial dots: sumsq, theta_pre, theta_post, Theta_res[0..3] ----
    float acc[7];
    acc[0] = xv.x * xv.x + xv.y * xv.y + xv.z * xv.z + xv.w * xv.w;
    acc[1] = xv.x * tp.x + xv.y * tp.y + xv.z * tp.z + xv.w * tp.w;
    acc[2] = xv.x * tq.x + xv.y * tq.y + xv.z * tq.z + xv.w * tq.w;
    acc[3] = xv.x * r0.x + xv.y * r0.y + xv.z * r0.z + xv.w * r0.w;
    acc[4] = xv.x * r1.x + xv.y * r1.y + xv.z * r1.z + xv.w * r1.w;
    acc[5] = xv.x * r2.x + xv.y * r2.y + xv.z * r2.z + xv.w * r2.w;
    acc[6] = xv.x * r3.x + xv.y * r3.y + xv.z * r3.z + xv.w * r3.w;

    // ---- wave(64)-wide butterfly reduction of all 7 ----
#pragma unroll
    for (int m = 1; m < 64; m <<= 1) {
#pragma unroll
        for (int k = 0; k < 7; ++k) acc[k] += __shfl_xor(acc[k], m, 64);
    }

    if (j == 0) {
        // F.normalize: x / max(||x||, 1e-12); dots scale linearly.
        float inv = 1.0f / fmaxf(sqrtf(acc[0]), 1e-12f);
#pragma unroll
        for (int k = 0; k < 6; ++k) sdots[s][k] = acc[1 + k] * inv;
    }
    __syncthreads();

    // ---- wave 0 only: tanh heads + 4x4 Sinkhorn (lane-redundant = free) ----
    if (s == 0) {
        const float apre = alpha_pre_p[0];
        const float apost = alpha_post_p[0];
        const float ares = alpha_res_p[0];

        const float dpre = 0.25f * (sdots[0][0] + sdots[1][0] + sdots[2][0] + sdots[3][0]);
        const float dpost = 0.25f * (sdots[0][1] + sdots[1][1] + sdots[2][1] + sdots[3][1]);
        const float dynp = tanhf(dpre);
        const float dynq = tanhf(dpost);

        float M[4][4];
#pragma unroll
        for (int r = 0; r < 4; ++r) {
            float dynr = tanhf(0.25f * (sdots[0][2 + r] + sdots[1][2 + r] +
                                        sdots[2][2 + r] + sdots[3][2 + r]));
            float a = ares * dynr;
#pragma unroll
            for (int c = 0; c < 4; ++c)
                M[r][c] = __expf((a + B_res[r * 4 + c]) * INV_TAU);
        }

#pragma unroll
        for (int it = 0; it < NIT; ++it) {
#pragma unroll
            for (int r = 0; r < 4; ++r) {
                float rs = M[r][0] + M[r][1] + M[r][2] + M[r][3];
                float rr = __builtin_amdgcn_rcpf(rs);
                M[r][0] *= rr; M[r][1] *= rr; M[r][2] *= rr; M[r][3] *= rr;
            }
#pragma unroll
            for (int c = 0; c < 4; ++c) {
                float cs = M[0][c] + M[1][c] + M[2][c] + M[3][c];
                float rr = __builtin_amdgcn_rcpf(cs);
                M[0][c] *= rr; M[1][c] *= rr; M[2][c] *= rr; M[3][c] *= rr;
            }
        }

        if (j == 0) {
            // static unrolled writes (no runtime-indexed register arrays)
#pragma unroll
            for (int r = 0; r < 4; ++r)
#pragma unroll
                for (int c = 0; c < 4; ++c) sH[r * 4 + c] = M[r][c];
#pragma unroll
            for (int c = 0; c < 4; ++c) sH[16 + c] = apost * dynq + b_post[c];
        }
        if (j < 4) out_hpre[(size_t)n * 4 + j] = apre * dynp + b_pre[j];
    }
    __syncthreads();

    // ---- output: out[s] = sum_t Hres[s][t]*x[t] + Hpost[s]*msg ----
    const float h0 = sH[s * 4 + 0];
    const float h1 = sH[s * 4 + 1];
    const float h2 = sH[s * 4 + 2];
    const float h3 = sH[s * 4 + 3];
    const float hp = sH[16 + s];

    float4 x0 = reinterpret_cast<const float4*>(&sx[0][0])[j];
    float4 x1 = reinterpret_cast<const float4*>(&sx[1][0])[j];
    float4 x2 = reinterpret_cast<const float4*>(&sx[2][0])[j];
    float4 x3 = reinterpret_cast<const float4*>(&sx[3][0])[j];
    float4 mv = reinterpret_cast<const float4*>(message_output + (size_t)n * DD)[j];

    float4 o;
    o.x = h0 * x0.x + h1 * x1.x + h2 * x2.x + h3 * x3.x + hp * mv.x;
    o.y = h0 * x0.y + h1 * x1.y + h2 * x2.y + h3 * x3.y + hp * mv.y;
    o.z = h0 * x0.z + h1 * x1.z + h2 * x2.z + h3 * x3.z + hp * mv.z;
    o.w = h0 * x0.w + h1 * x1.w + h2 * x2.w + h3 * x3.w + hp * mv.w;

    reinterpret_cast<float4*>(out_x + xbase + s * DD)[j] = o;
}

extern "C" void kernel_launch(void* const* d_in, const int* in_sizes, int n_in,
                              void* d_out, int out_size, void* d_ws, size_t ws_size,
                              hipStream_t stream) {
    const float* x_streams      = (const float*)d_in[0];
    const float* message_output = (const float*)d_in[1];
    const float* theta_pre      = (const float*)d_in[2];
    const float* b_pre          = (const float*)d_in[3];
    const float* theta_post     = (const float*)d_in[4];
    const float* b_post         = (const float*)d_in[5];
    const float* Theta_res      = (const float*)d_in[6];
    const float* B_res          = (const float*)d_in[7];
    const float* alpha_pre      = (const float*)d_in[8];
    const float* alpha_post     = (const float*)d_in[9];
    const float* alpha_res      = (const float*)d_in[10];

    const int N = in_sizes[0] / (SD * DD);

    float* out_x = (float*)d_out;
    float* out_hpre = out_x + (size_t)N * SD * DD;

    hyperconn_kernel<<<N, 256, 0, stream>>>(
        x_streams, message_output, theta_pre, b_pre, theta_post, b_post,
        Theta_res, B_res, alpha_pre, alpha_post, alpha_res, out_x, out_hpre);
}

// Round 2
// 165.015 us; speedup vs baseline: 1.9520x; 1.9520x over previous
//
#include <hip/hip_runtime.h>
#include <math.h>

// HyperConnection: N=100000, S=4, D=256.
// 1 wave per n, 4 n per 256-thread block. x register-resident per lane.
static constexpr int DD = 256;

__device__ __forceinline__ float tanh_fast(float x) {
    // tanh(x) = 1 - 2/(exp(2x)+1); |x| <= ~0.2 here -> ~1e-7 abs error
    float e = __expf(2.0f * x);
    return 1.0f - 2.0f * __builtin_amdgcn_rcpf(e + 1.0f);
}
__device__ __forceinline__ float dot4(float4 a, float4 b) {
    return a.x * b.x + a.y * b.y + a.z * b.z + a.w * b.w;
}
__device__ __forceinline__ float rl(float v, int l) {
    return __int_as_float(__builtin_amdgcn_readlane(__float_as_int(v), l));
}

__global__ __launch_bounds__(256) void hyperconn_kernel(
    const float* __restrict__ x_streams,       // (N,4,256)
    const float* __restrict__ message_output,  // (N,256)
    const float* __restrict__ theta_pre,       // (1,256)
    const float* __restrict__ b_pre,           // (1,4)
    const float* __restrict__ theta_post,      // (1,256)
    const float* __restrict__ b_post,          // (1,4)
    const float* __restrict__ Theta_res,       // (4,256)
    const float* __restrict__ B_res,           // (4,4)
    const float* __restrict__ alpha_pre_p,
    const float* __restrict__ alpha_post_p,
    const float* __restrict__ alpha_res_p,
    float* __restrict__ out_x,                 // (N,4,256)
    float* __restrict__ out_hpre,              // (N,4)
    int Ntot)
{
    const int lane = threadIdx.x & 63;
    const int w = threadIdx.x >> 6;
    const long long n = (long long)blockIdx.x * 4 + w;
    const bool valid = (n < (long long)Ntot);

    __shared__ float sdots[4][8];                      // 6 raw dots per n
    __shared__ __align__(16) float sM[4][16];          // H_res row-major
    __shared__ __align__(16) float sHpost[4][4];       // H_post per n

    // ---- loads: 4 x-rows + msg register-resident; weights (L1-hot) ----
    float4 x0, x1, x2, x3, mv;
    if (valid) {
        const float4* xp = reinterpret_cast<const float4*>(x_streams + n * (4 * DD));
        x0 = xp[0 * 64 + lane];
        x1 = xp[1 * 64 + lane];
        x2 = xp[2 * 64 + lane];
        x3 = xp[3 * 64 + lane];
        mv = reinterpret_cast<const float4*>(message_output + n * DD)[lane];
    } else {
        x0 = x1 = x2 = x3 = mv = make_float4(0.f, 0.f, 0.f, 0.f);
    }
    const float4 tp = reinterpret_cast<const float4*>(theta_pre)[lane];
    const float4 tq = reinterpret_cast<const float4*>(theta_post)[lane];
    const float4 r0 = reinterpret_cast<const float4*>(Theta_res + 0 * DD)[lane];
    const float4 r1 = reinterpret_cast<const float4*>(Theta_res + 1 * DD)[lane];
    const float4 r2 = reinterpret_cast<const float4*>(Theta_res + 2 * DD)[lane];
    const float4 r3 = reinterpret_cast<const float4*>(Theta_res + 3 * DD)[lane];

    // ---- per-row sumsq partials ----
    float ss0 = dot4(x0, x0), ss1 = dot4(x1, x1), ss2 = dot4(x2, x2), ss3 = dot4(x3, x3);

    // ---- reduce-scatter 4 values over 64 lanes: 7 shuffles total ----
    const bool b0 = (lane & 1) != 0;
    const bool b1 = (lane & 2) != 0;
    const bool b2 = (lane & 4) != 0;
    {
        float sA = b0 ? ss0 : ss2, sB = b0 ? ss1 : ss3;
        float gA = __shfl_xor(sA, 1, 64), gB = __shfl_xor(sB, 1, 64);
        float A0 = (b0 ? ss2 : ss0) + gA;
        float A1 = (b0 ? ss3 : ss1) + gB;
        float s2 = b1 ? A0 : A1;
        float g2 = __shfl_xor(s2, 2, 64);
        float T = (b1 ? A1 : A0) + g2;
        T += __shfl_xor(T, 4, 64);
        T += __shfl_xor(T, 8, 64);
        T += __shfl_xor(T, 16, 64);
        T += __shfl_xor(T, 32, 64);
        // lane&3 -> value: 0:ss0 1:ss2 2:ss1 3:ss3
        ss0 = rl(T, 0); ss2 = rl(T, 1); ss1 = rl(T, 2); ss3 = rl(T, 3);
    }
    // inv-norms with 1/4 pooling factor folded in
    const float in0 = 0.25f * __builtin_amdgcn_rsqf(fmaxf(ss0, 1e-24f));
    const float in1 = 0.25f * __builtin_amdgcn_rsqf(fmaxf(ss1, 1e-24f));
    const float in2 = 0.25f * __builtin_amdgcn_rsqf(fmaxf(ss2, 1e-24f));
    const float in3 = 0.25f * __builtin_amdgcn_rsqf(fmaxf(ss3, 1e-24f));

    // ---- pooled vector (per-lane float4) ----
    float4 p;
    p.x = in0 * x0.x + in1 * x1.x + in2 * x2.x + in3 * x3.x;
    p.y = in0 * x0.y + in1 * x1.y + in2 * x2.y + in3 * x3.y;
    p.z = in0 * x0.z + in1 * x1.z + in2 * x2.z + in3 * x3.z;
    p.w = in0 * x0.w + in1 * x1.w + in2 * x2.w + in3 * x3.w;

    // ---- 6 dots of pooled with weights ----
    float d0 = dot4(p, tp), d1 = dot4(p, tq);
    float d2 = dot4(p, r0), d3 = dot4(p, r1), d4 = dot4(p, r2), d5 = dot4(p, r3);

    // ---- reduce-scatter 6 values (pad to 8): 10 shuffles total ----
    {
        float sa = b0 ? d0 : d4, sb = b0 ? d1 : d5;
        float sc = b0 ? d2 : 0.0f, sd = b0 ? d3 : 0.0f;
        float ga = __shfl_xor(sa, 1, 64), gb = __shfl_xor(sb, 1, 64);
        float gc = __shfl_xor(sc, 1, 64), gd = __shfl_xor(sd, 1, 64);
        float B0 = (b0 ? d4 : d0) + ga;
        float B1 = (b0 ? d5 : d1) + gb;
        float B2 = (b0 ? 0.0f : d2) + gc;
        float B3 = (b0 ? 0.0f : d3) + gd;
        float s20 = b1 ? B0 : B2, s21 = b1 ? B1 : B3;
        float g20 = __shfl_xor(s20, 2, 64), g21 = __shfl_xor(s21, 2, 64);
        float C0 = (b1 ? B2 : B0) + g20;
        float C1 = (b1 ? B3 : B1) + g21;
        float s3 = b2 ? C0 : C1;
        float g3 = __shfl_xor(s3, 4, 64);
        float U = (b2 ? C1 : C0) + g3;
        U += __shfl_xor(U, 8, 64);
        U += __shfl_xor(U, 16, 64);
        U += __shfl_xor(U, 32, 64);
        // lane<8 owns value idx = 4*b0 + 2*b1 + b2 (idx 6,7 are pads)
        int idx = ((lane & 1) << 2) | (lane & 2) | ((lane & 4) >> 2);
        if (lane < 8 && idx < 6) sdots[w][idx] = U;
    }
    __syncthreads();

    // ---- phase B: wave 0 = 4 packed Sinkhorns; wave 1 = heads ----
    if (w == 0) {
        const int sw = lane >> 4, e = lane & 15, r = e >> 2;
        const float ares = alpha_res_p[0];
        float dres = tanh_fast(sdots[sw][2 + r]);
        float Mv = __expf((ares * dres + B_res[e]) * 10.0f);
#pragma unroll
        for (int it = 0; it < 10; ++it) {
            float a1 = Mv + __shfl_xor(Mv, 1, 64);
            float rs = a1 + __shfl_xor(a1, 2, 64);
            Mv *= __builtin_amdgcn_rcpf(rs);
            float c1 = Mv + __shfl_xor(Mv, 4, 64);
            float cs = c1 + __shfl_xor(c1, 8, 64);
            Mv *= __builtin_amdgcn_rcpf(cs);
        }
        sM[sw][e] = Mv;
    } else if (w == 1 && lane < 32) {
        const int sw = lane >> 3, h = (lane >> 2) & 1, c = lane & 3;
        float v = tanh_fast(sdots[sw][h]);
        if (h == 0) {
            long long nh = (long long)blockIdx.x * 4 + sw;
            if (nh < (long long)Ntot)
                out_hpre[nh * 4 + c] = alpha_pre_p[0] * v + b_pre[c];
        } else {
            sHpost[sw][c] = alpha_post_p[0] * v + b_post[c];
        }
    }
    __syncthreads();

    // ---- epilogue: out[s] = sum_t M[s][t]*x_t + hpost[s]*msg ----
    const float4 m0 = *reinterpret_cast<const float4*>(&sM[w][0]);
    const float4 m1 = *reinterpret_cast<const float4*>(&sM[w][4]);
    const float4 m2 = *reinterpret_cast<const float4*>(&sM[w][8]);
    const float4 m3 = *reinterpret_cast<const float4*>(&sM[w][12]);
    const float4 hp = *reinterpret_cast<const float4*>(&sHpost[w][0]);

    if (valid) {
        float4* op = reinterpret_cast<float4*>(out_x + n * (4 * DD));
        float4 o;
        o.x = m0.x * x0.x + m0.y * x1.x + m0.z * x2.x + m0.w * x3.x + hp.x * mv.x;
        o.y = m0.x * x0.y + m0.y * x1.y + m0.z * x2.y + m0.w * x3.y + hp.x * mv.y;
        o.z = m0.x * x0.z + m0.y * x1.z + m0.z * x2.z + m0.w * x3.z + hp.x * mv.z;
        o.w = m0.x * x0.w + m0.y * x1.w + m0.z * x2.w + m0.w * x3.w + hp.x * mv.w;
        op[0 * 64 + lane] = o;
        o.x = m1.x * x0.x + m1.y * x1.x + m1.z * x2.x + m1.w * x3.x + hp.y * mv.x;
        o.y = m1.x * x0.y + m1.y * x1.y + m1.z * x2.y + m1.w * x3.y + hp.y * mv.y;
        o.z = m1.x * x0.z + m1.y * x1.z + m1.z * x2.z + m1.w * x3.z + hp.y * mv.z;
        o.w = m1.x * x0.w + m1.y * x1.w + m1.z * x2.w + m1.w * x3.w + hp.y * mv.w;
        op[1 * 64 + lane] = o;
        o.x = m2.x * x0.x + m2.y * x1.x + m2.z * x2.x + m2.w * x3.x + hp.z * mv.x;
        o.y = m2.x * x0.y + m2.y * x1.y + m2.z * x2.y + m2.w * x3.y + hp.z * mv.y;
        o.z = m2.x * x0.z + m2.y * x1.z + m2.z * x2.z + m2.w * x3.z + hp.z * mv.z;
        o.w = m2.x * x0.w + m2.y * x1.w + m2.z * x2.w + m2.w * x3.w + hp.z * mv.w;
        op[2 * 64 + lane] = o;
        o.x = m3.x * x0.x + m3.y * x1.x + m3.z * x2.x + m3.w * x3.x + hp.w * mv.x;
        o.y = m3.x * x0.y + m3.y * x1.y + m3.z * x2.y + m3.w * x3.y + hp.w * mv.y;
        o.z = m3.x * x0.z + m3.y * x1.z + m3.z * x2.z + m3.w * x3.z + hp.w * mv.z;
        o.w = m3.x * x0.w + m3.y * x1.w + m3.z * x2.w + m3.w * x3.w + hp.w * mv.w;
        op[3 * 64 + lane] = o;
    }
}

extern "C" void kernel_launch(void* const* d_in, const int* in_sizes, int n_in,
                              void* d_out, int out_size, void* d_ws, size_t ws_size,
                              hipStream_t stream) {
    const float* x_streams      = (const float*)d_in[0];
    const float* message_output = (const float*)d_in[1];
    const float* theta_pre      = (const float*)d_in[2];
    const float* b_pre          = (const float*)d_in[3];
    const float* theta_post     = (const float*)d_in[4];
    const float* b_post         = (const float*)d_in[5];
    const float* Theta_res      = (const float*)d_in[6];
    const float* B_res          = (const float*)d_in[7];
    const float* alpha_pre      = (const float*)d_in[8];
    const float* alpha_post     = (const float*)d_in[9];
    const float* alpha_res      = (const float*)d_in[10];

    const int N = in_sizes[0] / (4 * DD);
    float* out_x = (float*)d_out;
    float* out_hpre = out_x + (size_t)N * 4 * DD;

    const int nblocks = (N + 3) / 4;
    hyperconn_kernel<<<nblocks, 256, 0, stream>>>(
        x_streams, message_output, theta_pre, b_pre, theta_post, b_post,
        Theta_res, B_res, alpha_pre, alpha_post, alpha_res, out_x, out_hpre, N);
}